// Round 1
// baseline (668.162 us; speedup 1.0000x reference)
//
#include <hip/hip_runtime.h>
#include <math.h>

// Problem constants (from reference)
#define C 81
#define REG 405    // C*5
#define OUTW 486   // C + C*5

__device__ __forceinline__ float wave_max(float v) {
    #pragma unroll
    for (int off = 32; off > 0; off >>= 1)
        v = fmaxf(v, __shfl_xor(v, off));
    return v;
}
__device__ __forceinline__ float wave_sum(float v) {
    #pragma unroll
    for (int off = 32; off > 0; off >>= 1)
        v += __shfl_xor(v, off);
    return v;
}

// One 64-lane wave per row; 4 rows per 256-thread block.
__global__ __launch_bounds__(256) void postproc_kernel(
    const float* __restrict__ logits,
    const float* __restrict__ regr,
    const float* __restrict__ prop,
    float* __restrict__ out,
    int n_rows)
{
    const int lane = threadIdx.x & 63;
    const int row  = blockIdx.x * 4 + (threadIdx.x >> 6);
    if (row >= n_rows) return;

    const float BBOX_CLIP = 4.135166556742356f;   // log(1000/16)
    const float RAD2DEG   = 57.29577951308232f;   // 180/pi

    // ---------- softmax over 81 logits ----------
    const float* lrow = logits + (long long)row * C;
    float x0 = lrow[lane];
    float x1 = (lane < C - 64) ? lrow[64 + lane] : -INFINITY;
    float m = wave_max(fmaxf(x0, x1));
    float e0 = __expf(x0 - m);
    float e1 = (lane < C - 64) ? __expf(x1 - m) : 0.0f;
    float s = wave_sum(e0 + e1);
    float inv = 1.0f / s;

    float* orow = out + (long long)row * OUTW;
    orow[lane] = e0 * inv;
    if (lane < C - 64) orow[64 + lane] = e1 * inv;

    // ---------- box decode ----------
    // proposal row: wave-uniform addresses -> scalar loads
    const float* prow = prop + (long long)row * 5;
    const float cx = prow[0], cy = prow[1], w = prow[2], h = prow[3], a = prow[4];

    const float* rrow = regr + (long long)row * REG;
    float* drow = orow + C;
    #pragma unroll 1
    for (int j = lane; j < REG; j += 64) {
        float v = rrow[j];
        int k = j % 5;
        float o;
        switch (k) {
          case 0:  o = fminf(fmaxf(fmaf(v * 0.1f, w, cx), 0.0f), 1023.0f); break;
          case 1:  o = fminf(fmaxf(fmaf(v * 0.1f, h, cy), 0.0f), 1023.0f); break;
          case 2:  o = __expf(fminf(v * 0.2f, BBOX_CLIP)) * w; break;
          case 3:  o = __expf(fminf(v * 0.2f, BBOX_CLIP)) * h; break;
          default: o = fmaf(v, RAD2DEG, a); break;
        }
        drow[j] = o;
    }
}

extern "C" void kernel_launch(void* const* d_in, const int* in_sizes, int n_in,
                              void* d_out, int out_size, void* d_ws, size_t ws_size,
                              hipStream_t stream) {
    const float* logits = (const float*)d_in[0];
    const float* regr   = (const float*)d_in[1];
    const float* prop   = (const float*)d_in[2];
    float* out = (float*)d_out;

    const int n_rows = in_sizes[0] / C;             // 200000
    const int blocks = (n_rows + 3) / 4;            // 4 rows per 256-thread block
    postproc_kernel<<<blocks, 256, 0, stream>>>(logits, regr, prop, out, n_rows);
}